// Round 8
// baseline (280.549 us; speedup 1.0000x reference)
//
#include <hip/hip_runtime.h>

// DigitCaps dynamic routing, MI355X — round 8: all-b barrier-free sweeps.
// Key change vs r3-r7 (all ~55-85 us/sweep): each wave covers ALL 64 b with
// 4 b-group MFMAs sharing one B-fragment -> Wt read ONCE per sweep (64 MB,
// was 256), 8 MFMA per wave-iter (was 4), no barriers/LDS/atomics/memsets.
//
// u_hat[b,j,i,p] = sum_q x[b,i,q] W[j,i,p,q];  b=64, i=2048, j=32, p=32, q=16
//   A-sweep:  s1 = (1/32) sum_i u_hat            -> s_part ; v1 = squash
//   D-sweep:  d[i][j][b] = sum_p v[b,j,p]*u_hat  (v = v1, then v1+v2)
//   softmax:  c[i][j][b] = softmax_j d           (per-thread row)
//   S-sweep:  s = sum_i c*u_hat                  -> s_part ; squash -> v2/out
// Pass-C logits = sum_p (v1+v2)*u_hat (linearity) -> only 2 D-sweeps.
//
// MFMA 16x16x32 bf16: A k0-15 = hi(x), k16-31 = lo residual; B k-halves
// replicate W => A-side fp32-exact, only W rounded once (absmax ~4e-3).
// Layouts: Wt[i][h][n][8] bf16 (h=q-half, n=j*32+p), xT2[i][g][b][8] bf16.

namespace {

using bfrag = __attribute__((ext_vector_type(8))) short;   // 8 bf16 = 4 VGPR
using ffrag = __attribute__((ext_vector_type(4))) float;   // 4 fp32

constexpr int I_DIM = 2048;
constexpr int B_DIM = 64;
constexpr int N_DIM = 1024;
constexpr int TI    = 16;          // i's per block
constexpr int NIT   = I_DIM / TI;  // 128 i-tiles

__device__ __forceinline__ unsigned short f2bf(float f) {
    unsigned int u = __float_as_uint(f);
    return (unsigned short)((u + 0x7fffu + ((u >> 16) & 1u)) >> 16);
}

template<int CTRL>
__device__ __forceinline__ float dppf(float x) {
    return __int_as_float(
        __builtin_amdgcn_update_dpp(0, __float_as_int(x), CTRL, 0xF, 0xF, true));
}
__device__ __forceinline__ float sum16(float x) {   // reduce within 16-lane row
    x += dppf<0x121>(x); x += dppf<0x122>(x);
    x += dppf<0x124>(x); x += dppf<0x128>(x);
    return x;
}

// ---------------- conversion kernels (r6/r7-proven layouts) ----------------

// Wt[i][h][n][8] <- W[j][i][p][q] fp32  (n = j*32+p, h = q-half)
__global__ __launch_bounds__(256)
void conv_w(const float* __restrict__ W, unsigned short* __restrict__ Wt) {
    const int t = blockIdx.x * 256 + threadIdx.x;          // (i,n)
    const int i = t >> 10, n = t & 1023;
    const float* src = W + ((((n >> 5) * I_DIM + i) * 32 + (n & 31)) << 4);
    unsigned int o[8];
    #pragma unroll
    for (int k = 0; k < 8; ++k)
        o[k] = (unsigned int)f2bf(src[2 * k]) | ((unsigned int)f2bf(src[2 * k + 1]) << 16);
    uint4* d0 = reinterpret_cast<uint4*>(Wt + (((size_t)i * 2 + 0) * 1024 + n) * 8);
    uint4* d1 = reinterpret_cast<uint4*>(Wt + (((size_t)i * 2 + 1) * 1024 + n) * 8);
    *d0 = make_uint4(o[0], o[1], o[2], o[3]);
    *d1 = make_uint4(o[4], o[5], o[6], o[7]);
}

// xT2[i][g][b][8] <- x[b][i][q] fp32  (g0/1 = hi q0-7/q8-15, g2/3 = lo residual)
__global__ __launch_bounds__(256)
void conv_x(const float* __restrict__ x, unsigned short* __restrict__ xT2) {
    const int t = blockIdx.x * 256 + threadIdx.x;          // (i,b)
    const int i = t >> 6, b = t & 63;
    const float* src = x + (((size_t)b * I_DIM + i) << 4);
    unsigned int o[16];
    #pragma unroll
    for (int k = 0; k < 8; ++k) {
        const float f0 = src[2 * k], f1 = src[2 * k + 1];
        const unsigned short h0 = f2bf(f0), h1 = f2bf(f1);
        const float l0 = f0 - __uint_as_float(((unsigned int)h0) << 16);
        const float l1 = f1 - __uint_as_float(((unsigned int)h1) << 16);
        o[k]     = (unsigned int)h0       | ((unsigned int)h1 << 16);
        o[8 + k] = (unsigned int)f2bf(l0) | ((unsigned int)f2bf(l1) << 16);
    }
    #pragma unroll
    for (int g = 0; g < 4; ++g) {
        uint4* dst = reinterpret_cast<uint4*>(xT2 + (((size_t)i * 4 + g) * 64 + b) * 8);
        *dst = make_uint4(o[4 * g], o[4 * g + 1], o[4 * g + 2], o[4 * g + 3]);
    }
}

// ---------------- MFMA sweeps (barrier-free, all-b) ----------------
// Block: 256 thr = 4 waves; wave = one j, ALL 64 b (4 bg), TI=16 i's.
// Grid: 1024 = 8 j-groups x 128 i-tiles; XCD-chunk swizzle puts all 8 jg of
// an i-tile on one XCD back-to-back -> x-slice dedups in that XCD's L2.
// MODE 0 (A): s[bg][t] accumulates u_hat via MFMA C-operand.
// MODE 1 (D): u -> dv[r] = sum_p v*u (DPP), lanes li<4 store d[i][j][b].
// MODE 2 (S): u -> s += c4[bg][r]*u (c broadcast float4 per bg).
template<int MODE>
__global__ __launch_bounds__(256, 4)
void caps_sweep(const unsigned short* __restrict__ Wt,   // [I][2][1024][8]
                const unsigned short* __restrict__ xT2,  // [I][4][64][8]
                const float* __restrict__ v_in,          // [64][32][32] (D)
                const float* __restrict__ c_in,          // [I][32][64]  (S)
                float* __restrict__ d_out,               // [I][32][64]  (D)
                float* __restrict__ sp_out)              // [NIT][64][1024] (A,S)
{
    const int tid = threadIdx.x;
    const int w  = tid >> 6;           // wave 0..3 (j within group)
    const int l  = tid & 63;
    const int g  = l >> 4;             // 16-lane group 0..3
    const int li = l & 15;

    // swizzle: XCD k owns V in [k*128,(k+1)*128); consecutive V = same i-tile,
    // consecutive jg -> co-timed on one XCD (bijective, 1024 % 8 == 0).
    const int bid = (int)blockIdx.x;
    const int V   = ((bid & 7) << 7) | (bid >> 3);
    const int it  = ((V >> 7) << 4) | ((V & 127) >> 3);   // 0..127
    const int jg  = V & 7;
    const int j   = (jg << 2) + w;                        // 0..31
    const int i0  = it << 4;
    const int ilast = i0 + TI - 1;

    // per-lane element offsets (shorts)
    const int aoff = ((g << 6) + li) << 3;                        // xT2: +i*2048
    const int boff = ((((g & 1) << 10) + (j << 5) + li)) << 3;    // Wt:  +i*16384

    float vr[4][4][2];   // [bg][r][t] = v[bg*16+g*4+r][j][t*16+li]  (D only)
    if (MODE == 1) {
        #pragma unroll
        for (int bg = 0; bg < 4; ++bg)
            #pragma unroll
            for (int r = 0; r < 4; ++r)
                #pragma unroll
                for (int t = 0; t < 2; ++t)
                    vr[bg][r][t] = v_in[((((bg << 4) + (g << 2) + r) << 5) + j) * 32
                                        + (t << 4) + li];
    }

    ffrag s[4][2];
    #pragma unroll
    for (int bg = 0; bg < 4; ++bg) {
        s[bg][0] = ffrag{0.f, 0.f, 0.f, 0.f};
        s[bg][1] = ffrag{0.f, 0.f, 0.f, 0.f};
    }

    bfrag A0[4], B0[2], A1[4], B1[2];

    auto loadf = [&](int i, bfrag (&A)[4], bfrag (&B)[2]) {
        const unsigned short* xa = xT2 + (size_t)i * 2048 + aoff;
        #pragma unroll
        for (int bg = 0; bg < 4; ++bg)
            A[bg] = *reinterpret_cast<const bfrag*>(xa + (bg << 7));
        const unsigned short* xb = Wt + (size_t)i * 16384 + boff;
        B[0] = *reinterpret_cast<const bfrag*>(xb);
        B[1] = *reinterpret_cast<const bfrag*>(xb + 128);
    };

    loadf(i0, A0, B0);   // prologue

    auto body = [&](int i, bfrag (&CA)[4], bfrag (&CB)[2],
                    bfrag (&NA)[4], bfrag (&NB)[2]) {
        ffrag c4[4];
        if (MODE == 2) {
            const float* cb = c_in + ((size_t)i << 11) + (j << 6) + (g << 2);
            #pragma unroll
            for (int bg = 0; bg < 4; ++bg)
                c4[bg] = *reinterpret_cast<const ffrag*>(cb + (bg << 4));
        }
        const int inx = (i < ilast) ? i + 1 : i;   // clamp (redundant reload ok)
        loadf(inx, NA, NB);
        asm volatile("" ::: "memory");

        #pragma unroll
        for (int bg = 0; bg < 4; ++bg) {
            if (MODE == 0) {
                s[bg][0] = __builtin_amdgcn_mfma_f32_16x16x32_bf16(CA[bg], CB[0], s[bg][0], 0, 0, 0);
                s[bg][1] = __builtin_amdgcn_mfma_f32_16x16x32_bf16(CA[bg], CB[1], s[bg][1], 0, 0, 0);
            } else {
                const ffrag z{0.f, 0.f, 0.f, 0.f};
                const ffrag u0 = __builtin_amdgcn_mfma_f32_16x16x32_bf16(CA[bg], CB[0], z, 0, 0, 0);
                const ffrag u1 = __builtin_amdgcn_mfma_f32_16x16x32_bf16(CA[bg], CB[1], z, 0, 0, 0);
                if (MODE == 1) {
                    // d[b][j] = sum_p v*u, p = t*16+li: in-lane 2 FMA + sum16
                    float d0 = sum16(u0[0] * vr[bg][0][0] + u1[0] * vr[bg][0][1]);
                    float d1 = sum16(u0[1] * vr[bg][1][0] + u1[1] * vr[bg][1][1]);
                    float d2 = sum16(u0[2] * vr[bg][2][0] + u1[2] * vr[bg][2][1]);
                    float d3 = sum16(u0[3] * vr[bg][3][0] + u1[3] * vr[bg][3][1]);
                    float sel = d0;
                    sel = (li == 1) ? d1 : sel;
                    sel = (li == 2) ? d2 : sel;
                    sel = (li == 3) ? d3 : sel;
                    if (li < 4)
                        d_out[((size_t)i << 11) + (j << 6) + (bg << 4) + (g << 2) + li] = sel;
                } else {
                    #pragma unroll
                    for (int r = 0; r < 4; ++r) {
                        s[bg][0][r] += c4[bg][r] * u0[r];
                        s[bg][1][r] += c4[bg][r] * u1[r];
                    }
                }
            }
        }
    };

    for (int cc = 0; cc < TI / 2; ++cc) {
        body(i0 + 2 * cc,     A0, B0, A1, B1);
        body(i0 + 2 * cc + 1, A1, B1, A0, B0);
    }

    if (MODE != 1) {
        const float sc = (MODE == 0) ? (1.f / 32.f) : 1.f;
        #pragma unroll
        for (int bg = 0; bg < 4; ++bg)
            #pragma unroll
            for (int t = 0; t < 2; ++t)
                #pragma unroll
                for (int r = 0; r < 4; ++r)
                    sp_out[((size_t)((it << 6) + (bg << 4) + (g << 2) + r) << 10)
                           + (j << 5) + (t << 4) + li] = s[bg][t][r] * sc;
    }
}

// c[i][j][b] = softmax_j d[i][j][b] — one thread per (i,b), row in registers
__global__ __launch_bounds__(256)
void softmax_dc(const float* __restrict__ d, float* __restrict__ c) {
    const int t = blockIdx.x * 256 + threadIdx.x;   // (i,b)
    const int i = t >> 6, b = t & 63;
    const float* dp = d + ((size_t)i << 11) + b;
    float v[32];
    float m = -1e30f;
    #pragma unroll
    for (int jx = 0; jx < 32; ++jx) { v[jx] = dp[jx << 6]; m = fmaxf(m, v[jx]); }
    float sm = 0.f;
    #pragma unroll
    for (int jx = 0; jx < 32; ++jx) { v[jx] = __expf(v[jx] - m); sm += v[jx]; }
    const float inv = 1.f / sm;
    float* cp = c + ((size_t)i << 11) + b;
    #pragma unroll
    for (int jx = 0; jx < 32; ++jx) cp[jx << 6] = v[jx] * inv;
}

// dst[row] = (base ? base[row] : 0) + squash(sum_it s_part[it][row]), row=(b,j)
__global__ __launch_bounds__(256)
void squash_reduce(const float* __restrict__ s_part,
                   const float* __restrict__ base,
                   float* __restrict__ dst) {
    const int tid = threadIdx.x;
    const int rr  = blockIdx.x * 8 + (tid >> 5);    // row 0..2047
    const int p   = tid & 31;
    const int b   = rr >> 5, jx = rr & 31;
    const float* sp = s_part + (size_t)b * N_DIM + (jx << 5) + p;
    float a0 = 0.f, a1 = 0.f, a2 = 0.f, a3 = 0.f;
    for (int it2 = 0; it2 < NIT; it2 += 4) {
        a0 += sp[(size_t)(it2 + 0) << 16];
        a1 += sp[(size_t)(it2 + 1) << 16];
        a2 += sp[(size_t)(it2 + 2) << 16];
        a3 += sp[(size_t)(it2 + 3) << 16];
    }
    const float sv = (a0 + a1) + (a2 + a3);
    float n2 = sv * sv;
    n2 = sum16(n2);
    n2 += __shfl_xor(n2, 16);
    const float scl = n2 / ((1.f + n2) * sqrtf(n2 + 1e-7f));
    dst[rr * 32 + p] = (base ? base[rr * 32 + p] : 0.f) + scl * sv;
}

} // namespace

extern "C" void kernel_launch(void* const* d_in, const int* in_sizes, int n_in,
                              void* d_out, int out_size, void* d_ws, size_t ws_size,
                              hipStream_t stream) {
    const float* x = (const float*)d_in[0];   // [64, 2048, 16]
    const float* W = (const float*)d_in[1];   // [32, 2048, 32, 16]
    float* out = (float*)d_out;               // [64, 32, 32]

    const size_t needW = (size_t)I_DIM * 2 * 1024 * 8 * 2;    // 64 MB bf16 Wt
    const size_t needX = (size_t)I_DIM * 4 * 64 * 8 * 2;      //  8 MB bf16 xT2
    const size_t needD = (size_t)I_DIM * 32 * 64 * 4;         // 16 MB d / c
    const size_t needP = (size_t)NIT * B_DIM * N_DIM * 4;     // 32 MB partials
    const size_t needV = (size_t)B_DIM * N_DIM * 4;           // 256 KB

    char* pp = (char*)d_ws;
    unsigned short* Wt  = (unsigned short*)pp; pp += needW;
    unsigned short* xT2 = (unsigned short*)pp; pp += needX;
    float* dbuf   = (float*)pp; pp += needD;
    float* cbuf   = (float*)pp; pp += needD;
    float* s_part = (float*)pp; pp += needP;
    float* v1     = (float*)pp; pp += needV;
    float* vs     = (float*)pp;
    (void)ws_size;

    conv_x<<<(I_DIM * B_DIM) / 256, 256, 0, stream>>>(x, xT2);
    conv_w<<<(I_DIM * N_DIM) / 256, 256, 0, stream>>>(W, Wt);

    const dim3 rg(1024), rb(256);
    const dim3 sg(512), sb(256);
    const dim3 qg(256), qb(256);

    // pass A: uniform c = 1/32
    caps_sweep<0><<<rg, rb, 0, stream>>>(Wt, xT2, nullptr, nullptr, nullptr, s_part);
    squash_reduce<<<qg, qb, 0, stream>>>(s_part, nullptr, v1);

    // pass B: d1 = sum_p v1*u_hat ; c2 = softmax(d1) ; s2
    caps_sweep<1><<<rg, rb, 0, stream>>>(Wt, xT2, v1, nullptr, dbuf, nullptr);
    softmax_dc<<<sg, sb, 0, stream>>>(dbuf, cbuf);
    caps_sweep<2><<<rg, rb, 0, stream>>>(Wt, xT2, nullptr, cbuf, nullptr, s_part);
    squash_reduce<<<qg, qb, 0, stream>>>(s_part, v1, vs);     // vs = v1 + v2

    // pass C: logits = sum_p (v1+v2)*u_hat (linearity)
    caps_sweep<1><<<rg, rb, 0, stream>>>(Wt, xT2, vs, nullptr, dbuf, nullptr);
    softmax_dc<<<sg, sb, 0, stream>>>(dbuf, cbuf);
    caps_sweep<2><<<rg, rb, 0, stream>>>(Wt, xT2, nullptr, cbuf, nullptr, s_part);
    squash_reduce<<<qg, qb, 0, stream>>>(s_part, nullptr, out);
}